// Round 19
// baseline (387.490 us; speedup 1.0000x reference)
//
#include <hip/hip_runtime.h>
#include <hip/hip_bf16.h>

typedef unsigned short ushort_t;
typedef short short8 __attribute__((ext_vector_type(8)));
typedef unsigned short ushort8 __attribute__((ext_vector_type(8)));
typedef unsigned short ushortx4 __attribute__((ext_vector_type(4)));
typedef float fx4 __attribute__((ext_vector_type(4)));
typedef int ix4 __attribute__((ext_vector_type(4)));

#define MFMA(a, b, c) __builtin_amdgcn_mfma_f32_16x16x32_bf16((a), (b), (c), 0, 0, 0)

// scores were (A+B)/sqrt(64); fold 0.125*log2(e) into q so softmax is raw exp2
#define QSCALE 0.18033688011112042f

__device__ __forceinline__ ushort_t f2bf(float f) {
  __hip_bfloat16 h = __float2bfloat16(f);
  return *(ushort_t*)&h;
}
__device__ __forceinline__ float bf2f(ushort_t h) {
  union { unsigned u; float f; } c; c.u = ((unsigned)h) << 16;
  return c.f;
}
__device__ __forceinline__ void gload16(const ushort_t* g, ushort_t* l) {
  __builtin_amdgcn_global_load_lds((const __attribute__((address_space(1))) void*)g,
                                   (__attribute__((address_space(3))) void*)l, 16, 0, 0);
}
template <int R>
__device__ __forceinline__ float fp8sel(unsigned u) {
  return __builtin_amdgcn_cvt_f32_fp8((int)u, R);
}
__device__ __forceinline__ fx4 fp8x4(unsigned u) {
  fx4 r;
  r[0] = fp8sel<0>(u); r[1] = fp8sel<1>(u); r[2] = fp8sel<2>(u); r[3] = fp8sel<3>(u);
  return r;
}

// ---------------- fused prep: weight cvt (blocks 0..4095), LN (4096..12287),
// ---------------- maskpack (12288..20479). All 256-thread parts.
__global__ __launch_bounds__(256) void prep_kernel(const float* __restrict__ wq,
                                                   const float* __restrict__ wk,
                                                   const float* __restrict__ wv,
                                                   const float* __restrict__ wo,
                                                   ushort_t* __restrict__ wqb,
                                                   ushort_t* __restrict__ wkb,
                                                   ushort_t* __restrict__ wvb,
                                                   ushort_t* __restrict__ wob,
                                                   const float* __restrict__ x,
                                                   const float* __restrict__ sc,
                                                   const float* __restrict__ bi,
                                                   ushort_t* __restrict__ xn,
                                                   const int* __restrict__ mask,
                                                   unsigned* __restrict__ bits) {
  __shared__ float red[8];
  __shared__ unsigned char nib[256];
  int bid = blockIdx.x, tid = threadIdx.x;
  if (bid < 4096) {
    const float* src = (bid < 1024) ? wq : (bid < 2048) ? wk : (bid < 3072) ? wv : wo;
    ushort_t* dst = (bid < 1024) ? wqb : (bid < 2048) ? wkb : (bid < 3072) ? wvb : wob;
    int i = (bid & 1023) * 256 + tid;
    fx4 v = *(const fx4*)&src[(size_t)i * 4];
    ushortx4 o;
#pragma unroll
    for (int j = 0; j < 4; ++j) o[j] = f2bf(v[j]);
    *(ushortx4*)&dst[(size_t)i * 4] = o;
  } else if (bid < 12288) {
    int row = bid - 4096;
    const float* xr = x + (size_t)row * 1024;
    fx4 v = *(const fx4*)&xr[tid * 4];
    float s = v[0] + v[1] + v[2] + v[3];
    float s2 = v[0] * v[0] + v[1] * v[1] + v[2] * v[2] + v[3] * v[3];
#pragma unroll
    for (int m = 32; m >= 1; m >>= 1) {
      s += __shfl_xor(s, m);
      s2 += __shfl_xor(s2, m);
    }
    int wave = tid >> 6;
    if ((tid & 63) == 0) { red[wave * 2] = s; red[wave * 2 + 1] = s2; }
    __syncthreads();
    s = red[0] + red[2] + red[4] + red[6];
    s2 = red[1] + red[3] + red[5] + red[7];
    float mu = s * (1.f / 1024.f);
    float var = s2 * (1.f / 1024.f) - mu * mu;
    float rs = rsqrtf(var + 1e-5f);
    fx4 scv = *(const fx4*)&sc[tid * 4];
    fx4 biv = *(const fx4*)&bi[tid * 4];
    ushortx4 o;
#pragma unroll
    for (int j = 0; j < 4; ++j) o[j] = f2bf((v[j] - mu) * rs * scv[j] + biv[j]);
    *(ushortx4*)&xn[(size_t)row * 1024 + tid * 4] = o;
  } else {
    int row = bid - 12288;
    ix4 m = *(const ix4*)&mask[(size_t)row * 1024 + tid * 4];
    nib[tid] = (unsigned char)((m[0] != 0 ? 1 : 0) | (m[1] != 0 ? 2 : 0) |
                               (m[2] != 0 ? 4 : 0) | (m[3] != 0 ? 8 : 0));
    __syncthreads();
    if (tid < 32) {
      unsigned w = 0;
#pragma unroll
      for (int j = 0; j < 8; ++j) w |= ((unsigned)nib[tid * 8 + j]) << (j * 4);
      bits[(size_t)row * 32 + tid] = w;
    }
  }
}

// ---- GEMM: C[M][N] = (A @ B^T + bias(n)) * scale(n); bias/scale select per 1024-col group ----
template <int F32OUT>
__global__ __launch_bounds__(256) void gemm_bt(const ushort_t* __restrict__ A,
                                               const ushort_t* __restrict__ B,
                                               const float* __restrict__ b0,
                                               const float* __restrict__ b1,
                                               const float* __restrict__ b2, void* C,
                                               int M, int N, int K, float os0, float os1) {
  __shared__ ushort_t lA[4096];  // [128][32] linear
  __shared__ ushort_t lB[4096];
  int bm = blockIdx.y * 128, bn = blockIdx.x * 128;
  int tid = threadIdx.x;
  int wave = tid >> 6, lane = tid & 63;
  int wm = (wave >> 1) * 64, wn = (wave & 1) * 64;
  int l15 = lane & 15, lg = lane >> 4;
  int r0 = tid >> 2, c0 = (tid & 3) * 8;
  int g1 = 256 + tid, r1 = g1 >> 2, c1 = (g1 & 3) * 8;
  int lb0 = (wave * 64) * 8;
  int lb1 = (256 + wave * 64) * 8;
  fx4 acc[4][4] = {};
  for (int k0 = 0; k0 < K; k0 += 32) {
    __syncthreads();
    gload16(&A[(size_t)(bm + r0) * K + k0 + c0], &lA[lb0]);
    gload16(&A[(size_t)(bm + r1) * K + k0 + c1], &lA[lb1]);
    gload16(&B[(size_t)(bn + r0) * K + k0 + c0], &lB[lb0]);
    gload16(&B[(size_t)(bn + r1) * K + k0 + c1], &lB[lb1]);
    __syncthreads();
    short8 af[4], bf[4];
#pragma unroll
    for (int i = 0; i < 4; ++i) af[i] = *(const short8*)&lA[(wm + i * 16 + l15) * 32 + lg * 8];
#pragma unroll
    for (int i = 0; i < 4; ++i) bf[i] = *(const short8*)&lB[(wn + i * 16 + l15) * 32 + lg * 8];
#pragma unroll
    for (int i = 0; i < 4; ++i)
#pragma unroll
      for (int j = 0; j < 4; ++j) acc[i][j] = MFMA(af[i], bf[j], acc[i][j]);
  }
#pragma unroll
  for (int j = 0; j < 4; ++j) {
    int n = bn + wn + j * 16 + l15;
    const float* bp = (n < 1024) ? b0 : (n < 2048) ? b1 : b2;
    float bv = bp[n & 1023];
    float sc = (n < 1024) ? os0 : os1;
#pragma unroll
    for (int i = 0; i < 4; ++i) {
      int mr = bm + wm + i * 16 + lg * 4;
#pragma unroll
      for (int r = 0; r < 4; ++r) {
        float val = (acc[i][j][r] + bv) * sc;
        if (F32OUT)
          ((float*)C)[(size_t)(mr + r) * N + n] = val;
        else
          ((ushort_t*)C)[(size_t)(mr + r) * N + n] = f2bf(val);
      }
    }
  }
}

// ---------------- B_all[bh][t][s] (fp8 e4m3) = sum_d q[...] * pos_k[t,s,d] ----------------
// v9: one block per t (grid 1024); each wave covers 128 s via two sequential
// 4-chunk groups (r6-proven g-loop) -> per-row stores span a full 128-B L2 line
// per wave (fp8 half-line write-amp fix) and q-staging per t halves.
__device__ __forceinline__ void loadset(const float* base, int c, fx4* r) {
  const float* p = base + (size_t)c * 1024;
  r[0] = *(const fx4*)p;
  r[1] = *(const fx4*)(p + 4);
  r[2] = *(const fx4*)(p + 32);
  r[3] = *(const fx4*)(p + 36);
}
__device__ __forceinline__ void cvtset(const fx4* r, short8& f0, short8& f1) {
#pragma unroll
  for (int j = 0; j < 4; ++j) {
    f0[j] = (short)f2bf(r[0][j]); f0[j + 4] = (short)f2bf(r[1][j]);
    f1[j] = (short)f2bf(r[2][j]); f1[j + 4] = (short)f2bf(r[3][j]);
  }
}

__global__ __launch_bounds__(512, 4) void ball_kernel(const ushort_t* __restrict__ qkv,
                                                      const float* __restrict__ pos_k,
                                                      unsigned char* __restrict__ B8) {
  __shared__ ushort_t lq[128 * 64];  // rows of 128 B, col-byte ^= (row&7)<<4
  int t = blockIdx.x;
  int tid = threadIdx.x, wave = tid >> 6, lane = tid & 63, l15 = lane & 15, lg = lane >> 4;
  const float* pk = pos_k + (size_t)t * 65536;
  int sw = wave * 128;  // this wave: s in [sw, sw+128)
  const float* base = pk + (size_t)(sw + l15) * 64 + lg * 8;

  fx4 raw[4][4];
#pragma unroll
  for (int c = 0; c < 4; ++c) loadset(base, c, raw[c]);

  // stage q[t]: 128 bh-rows x 64 bf16 (16 KB), swizzled (covers prologue latency)
#pragma unroll
  for (int it = 0; it < 2; ++it) {
    int u = tid + it * 512;           // 0..1023 16B-units
    int row = u >> 3, cu = u & 7;     // row=bh, cu=16B col unit
    ushort8 vv = *(const ushort8*)&qkv[((size_t)((row >> 4) * 1024 + t)) * 3072 + (row & 15) * 64 + cu * 8];
    *(ushort8*)&lq[(row * 128 + ((cu * 16) ^ ((row & 7) << 4))) >> 1] = vv;
  }
  __syncthreads();

  short8 af0[4], af1[4];
#pragma unroll
  for (int c = 0; c < 4; ++c) cvtset(raw[c], af0[c], af1[c]);

#pragma unroll
  for (int g = 0; g < 2; ++g) {
    if (g == 0) {
#pragma unroll
      for (int c = 0; c < 4; ++c) loadset(base, 4 + c, raw[c]);
    }
    __builtin_amdgcn_sched_barrier(0);
#pragma unroll
    for (int j = 0; j < 8; ++j) {
      int row_ = j * 16 + l15;
      int cb_ = (row_ & 7) << 4;
      short8 q0 = *(const short8*)&lq[(row_ * 128 + ((lg * 16) ^ cb_)) >> 1];
      short8 q1 = *(const short8*)&lq[(row_ * 128 + ((64 + lg * 16) ^ cb_)) >> 1];
      fx4 z = {};
      size_t rb = ((size_t)row_ << 20) + (size_t)t * 1024 + (size_t)(sw + g * 64);
#pragma unroll
      for (int c = 0; c < 4; ++c) {
        fx4 a = MFMA(af0[c], q0, z);
        a = MFMA(af1[c], q1, a);
        int u = __builtin_amdgcn_cvt_pk_fp8_f32(a[0], a[1], 0, false);
        u = __builtin_amdgcn_cvt_pk_fp8_f32(a[2], a[3], u, true);
        *(unsigned*)&B8[rb + c * 16 + lg * 4] = (unsigned)u;
      }
    }
    __builtin_amdgcn_sched_barrier(0);
    if (g == 0) {
#pragma unroll
      for (int c = 0; c < 4; ++c) cvtset(raw[c], af0[c], af1[c]);
    }
  }
}

// ---------------- flash attention v8 (r16 config): 256 thr, 2 t-tiles/wave ----------------
__global__ __launch_bounds__(256) void attn_kernel(const ushort_t* __restrict__ qkv,
                                                   const unsigned char* __restrict__ B8,
                                                   const unsigned* __restrict__ mbits,
                                                   ushort_t* __restrict__ out) {
  __shared__ ushort_t lK[64][72];
  __shared__ ushort_t lVt[64][72];
  __shared__ ushort_t lP[4][2][16][72];
  int bh = blockIdx.y, b = bh >> 4, h = bh & 15;
  int t0 = blockIdx.x * 128;
  int tid = threadIdx.x, wave = tid >> 6, lane = tid & 63, l15 = lane & 15, lg = lane >> 4;
  int twA = t0 + wave * 16, twB = twA + 64;
  short8 qfA[2], qfB[2];
#pragma unroll
  for (int ks = 0; ks < 2; ++ks) {
    qfA[ks] = *(const short8*)&qkv[((size_t)(b * 1024 + twA + l15)) * 3072 + h * 64 + ks * 32 + lg * 8];
    qfB[ks] = *(const short8*)&qkv[((size_t)(b * 1024 + twB + l15)) * 3072 + h * 64 + ks * 32 + lg * 8];
  }
  fx4 oA[4] = {}, oB[4] = {};
  float lsumA = 0.f, lsumB = 0.f;
  const unsigned* mrowA = &mbits[((size_t)b * 1024 + twA + l15) * 32];
  const unsigned* mrowB = &mbits[((size_t)b * 1024 + twB + l15) * 32];
  size_t ballA = ((size_t)bh * 1024 + twA + l15) * 1024;
  size_t ballB = ((size_t)bh * 1024 + twB + l15) * 1024;

  int rs = tid >> 3, c8g = tid & 7, c8 = c8g * 8;  // staging: rows rs, rs+32
  const ushort_t* kbase = &qkv[((size_t)(b * 1024) + rs) * 3072 + 1024 + h * 64 + c8];
  const ushort_t* vbase = &qkv[((size_t)(b * 1024) + rs) * 3072 + 2048 + h * 64 + c8];
  ushort8 kr0 = *(const ushort8*)(kbase);
  ushort8 kr1 = *(const ushort8*)(kbase + 32 * 3072);
  ushort8 vr0 = *(const ushort8*)(vbase);
  ushort8 vr1 = *(const ushort8*)(vbase + 32 * 3072);
  int vs0 = (rs + 8 * c8g) & 63;        // rotated s-slot for row rs
  int vs1 = (rs + 32 + 8 * c8g) & 63;   // rotated s-slot for row rs+32

  // prefetched B_all (fp8) + mask for s0 = 0
  unsigned n8A[4], n8B[4];
#pragma unroll
  for (int mf = 0; mf < 4; ++mf) {
    n8A[mf] = *(const unsigned*)&B8[ballA + mf * 16 + lg * 4];
    n8B[mf] = *(const unsigned*)&B8[ballB + mf * 16 + lg * 4];
  }
  uint2 nmA = *(const uint2*)&mrowA[0];
  uint2 nmB = *(const uint2*)&mrowB[0];

  for (int s0 = 0; s0 < 1024; s0 += 64) {
    __syncthreads();
    *(ushort8*)&lK[rs][c8] = kr0;
    *(ushort8*)&lK[rs + 32][c8] = kr1;
#pragma unroll
    for (int j = 0; j < 8; ++j) {
      lVt[c8 + j][vs0] = vr0[j];
      lVt[c8 + j][vs1] = vr1[j];
    }
    __syncthreads();
    if (s0 + 64 < 1024) {
      size_t off = (size_t)(s0 + 64) * 3072;
      kr0 = *(const ushort8*)(kbase + off);
      kr1 = *(const ushort8*)(kbase + off + 32 * 3072);
      vr0 = *(const ushort8*)(vbase + off);
      vr1 = *(const ushort8*)(vbase + off + 32 * 3072);
    }
    __builtin_amdgcn_sched_barrier(0);
    unsigned long long wbA = ((unsigned long long)nmA.y << 32) | nmA.x;
    unsigned long long wbB = ((unsigned long long)nmB.y << 32) | nmB.x;
    // S^T tiles: kf read once, feeds both tiles (prescaled by QSCALE)
    float pA[16], pB[16];
#pragma unroll
    for (int mf = 0; mf < 4; ++mf) {
      short8 kf0 = *(const short8*)&lK[mf * 16 + l15][lg * 8];
      short8 kf1 = *(const short8*)&lK[mf * 16 + l15][32 + lg * 8];
      fx4 cA = {}, cB = {};
      cA = MFMA(kf0, qfA[0], cA);
      cA = MFMA(kf1, qfA[1], cA);
      cB = MFMA(kf0, qfB[0], cB);
      cB = MFMA(kf1, qfB[1], cB);
      fx4 dA = fp8x4(n8A[mf]);
      fx4 dB = fp8x4(n8B[mf]);
#pragma unroll
      for (int r = 0; r < 4; ++r) {
        pA[mf * 4 + r] = exp2f(cA[r] + dA[r]);
        pB[mf * 4 + r] = exp2f(cB[r] + dB[r]);
      }
    }
    // mask slow path (all-ones rows skip)
    if (!__all((wbA == ~0ull) && (wbB == ~0ull))) {
#pragma unroll
      for (int i = 0; i < 16; ++i) {
        int sl = (i >> 2) * 16 + lg * 4 + (i & 3);
        if (!((wbA >> sl) & 1ull)) pA[i] = 0.f;
        if (!((wbB >> sl) & 1ull)) pB[i] = 0.f;
      }
    }
    // prefetch next iteration's B_all + mask (lands during PV + next staging)
    if (s0 + 64 < 1024) {
#pragma unroll
      for (int mf = 0; mf < 4; ++mf) {
        n8A[mf] = *(const unsigned*)&B8[ballA + s0 + 64 + mf * 16 + lg * 4];
        n8B[mf] = *(const unsigned*)&B8[ballB + s0 + 64 + mf * 16 + lg * 4];
      }
      nmA = *(const uint2*)&mrowA[(s0 + 64) >> 5];
      nmB = *(const uint2*)&mrowB[(s0 + 64) >> 5];
    }
    __builtin_amdgcn_sched_barrier(0);
    float psA = 0.f, psB = 0.f;
#pragma unroll
    for (int i = 0; i < 16; ++i) { psA += pA[i]; psB += pB[i]; }
    lsumA += psA;
    lsumB += psB;
    // pack P -> lP (both tiles)
#pragma unroll
    for (int mf = 0; mf < 4; ++mf) {
      ushortx4 pk4A, pk4B;
#pragma unroll
      for (int r = 0; r < 4; ++r) { pk4A[r] = f2bf(pA[mf * 4 + r]); pk4B[r] = f2bf(pB[mf * 4 + r]); }
      *(ushortx4*)&lP[wave][0][l15][mf * 16 + lg * 4] = pk4A;
      *(ushortx4*)&lP[wave][1][l15][mf * 16 + lg * 4] = pk4B;
    }
    // PV: vf read once, feeds both tiles
#pragma unroll
    for (int ks = 0; ks < 2; ++ks) {
      short8 pfA = *(const short8*)&lP[wave][0][l15][ks * 32 + lg * 8];
      short8 pfB = *(const short8*)&lP[wave][1][l15][ks * 32 + lg * 8];
#pragma unroll
      for (int nf = 0; nf < 4; ++nf) {
        int d_ = nf * 16 + l15;
        int sb_ = (ks * 32 + lg * 8 + 8 * (d_ >> 3)) & 63;
        short8 vf = *(const short8*)&lVt[d_][sb_];
        oA[nf] = MFMA(pfA, vf, oA[nf]);
        oB[nf] = MFMA(pfB, vf, oB[nf]);
      }
    }
  }
  // final denominators
  lsumA += __shfl_xor(lsumA, 16);
  lsumA += __shfl_xor(lsumA, 32);
  lsumB += __shfl_xor(lsumB, 16);
  lsumB += __shfl_xor(lsumB, 32);
  float rlA = (lsumA > 0.f) ? 1.f / lsumA : 0.f;
  float rlB = (lsumB > 0.f) ? 1.f / lsumB : 0.f;
  float rwA[4], rwB[4];
#pragma unroll
  for (int r = 0; r < 4; ++r) {
    rwA[r] = __shfl(rlA, lg * 4 + r);
    rwB[r] = __shfl(rlB, lg * 4 + r);
  }
#pragma unroll
  for (int nf = 0; nf < 4; ++nf)
#pragma unroll
    for (int r = 0; r < 4; ++r) {
      out[((size_t)(b * 1024 + twA + lg * 4 + r)) * 1024 + h * 64 + nf * 16 + l15] =
          f2bf(oA[nf][r] * rwA[r]);
      out[((size_t)(b * 1024 + twB + lg * 4 + r)) * 1024 + h * 64 + nf * 16 + l15] =
          f2bf(oB[nf][r] * rwB[r]);
    }
}

extern "C" void kernel_launch(void* const* d_in, const int* in_sizes, int n_in, void* d_out,
                              int out_size, void* d_ws, size_t ws_size, hipStream_t stream) {
  (void)in_sizes; (void)n_in; (void)out_size; (void)ws_size;
  const float* x = (const float*)d_in[0];
  const float* pos_k = (const float*)d_in[1];
  const int* mask = (const int*)d_in[2];
  const float* ln_scale = (const float*)d_in[3];
  const float* ln_bias = (const float*)d_in[4];
  const float* wq = (const float*)d_in[5];
  const float* bq = (const float*)d_in[6];
  const float* wk = (const float*)d_in[7];
  const float* bk = (const float*)d_in[8];
  const float* wv = (const float*)d_in[9];
  const float* bv = (const float*)d_in[10];
  const float* wo = (const float*)d_in[11];
  const float* bo = (const float*)d_in[12];
  float* out = (float*)d_out;
  char* ws = (char*)d_ws;
  const size_t MB = 1ull << 20;
  ushort_t* xn = (ushort_t*)(ws + 0 * MB);    // 16 MB
  ushort_t* qkv = (ushort_t*)(ws + 16 * MB);  // 48 MB fused [8192][3072] (q|k|v)
  ushort_t* ao = (ushort_t*)(ws + 64 * MB);   // 16 MB
  ushort_t* wqb = (ushort_t*)(ws + 80 * MB);  // wq|wk|wv contiguous = [3072][1024]
  ushort_t* wkb = (ushort_t*)(ws + 82 * MB);
  ushort_t* wvb = (ushort_t*)(ws + 84 * MB);
  ushort_t* wob = (ushort_t*)(ws + 86 * MB);
  unsigned char* ball8 = (unsigned char*)(ws + 88 * MB);  // 128 MB fp8
  unsigned* mbits = (unsigned*)(ws + 216 * MB);  // 1 MB own region (ws >= 344 MB, r0)

  prep_kernel<<<20480, 256, 0, stream>>>(wq, wk, wv, wo, wqb, wkb, wvb, wob, x, ln_scale,
                                         ln_bias, xn, mask, mbits);
  // fused QKV GEMM: N = 3072, q-columns prescaled by QSCALE
  gemm_bt<0><<<dim3(24, 64), 256, 0, stream>>>(xn, wqb, bq, bk, bv, qkv, 8192, 3072, 1024,
                                               QSCALE, 1.f);
  ball_kernel<<<1024, 512, 0, stream>>>(qkv, pos_k, ball8);
  attn_kernel<<<dim3(8, 128), 256, 0, stream>>>(qkv, ball8, mbits, ao);
  gemm_bt<1><<<dim3(8, 64), 256, 0, stream>>>(ao, wob, bo, bo, bo, out, 8192, 1024, 1024,
                                              1.f, 1.f);
}

// Round 20
// 351.468 us; speedup vs baseline: 1.1025x; 1.1025x over previous
//
#include <hip/hip_runtime.h>
#include <hip/hip_bf16.h>

typedef unsigned short ushort_t;
typedef short short8 __attribute__((ext_vector_type(8)));
typedef unsigned short ushort8 __attribute__((ext_vector_type(8)));
typedef unsigned short ushortx4 __attribute__((ext_vector_type(4)));
typedef float fx4 __attribute__((ext_vector_type(4)));
typedef int ix4 __attribute__((ext_vector_type(4)));

#define MFMA(a, b, c) __builtin_amdgcn_mfma_f32_16x16x32_bf16((a), (b), (c), 0, 0, 0)

// scores were (A+B)/sqrt(64); fold 0.125*log2(e) into q so softmax is raw exp2
#define QSCALE 0.18033688011112042f

__device__ __forceinline__ ushort_t f2bf(float f) {
  __hip_bfloat16 h = __float2bfloat16(f);
  return *(ushort_t*)&h;
}
__device__ __forceinline__ float bf2f(ushort_t h) {
  union { unsigned u; float f; } c; c.u = ((unsigned)h) << 16;
  return c.f;
}
__device__ __forceinline__ void gload16(const ushort_t* g, ushort_t* l) {
  __builtin_amdgcn_global_load_lds((const __attribute__((address_space(1))) void*)g,
                                   (__attribute__((address_space(3))) void*)l, 16, 0, 0);
}
template <int R>
__device__ __forceinline__ float fp8sel(unsigned u) {
  return __builtin_amdgcn_cvt_f32_fp8((int)u, R);
}
__device__ __forceinline__ fx4 fp8x4(unsigned u) {
  fx4 r;
  r[0] = fp8sel<0>(u); r[1] = fp8sel<1>(u); r[2] = fp8sel<2>(u); r[3] = fp8sel<3>(u);
  return r;
}

// ---------------- fused prep: weight cvt (blocks 0..4095), LN (4096..12287),
// ---------------- maskpack (12288..20479). All 256-thread parts.
__global__ __launch_bounds__(256) void prep_kernel(const float* __restrict__ wq,
                                                   const float* __restrict__ wk,
                                                   const float* __restrict__ wv,
                                                   const float* __restrict__ wo,
                                                   ushort_t* __restrict__ wqb,
                                                   ushort_t* __restrict__ wkb,
                                                   ushort_t* __restrict__ wvb,
                                                   ushort_t* __restrict__ wob,
                                                   const float* __restrict__ x,
                                                   const float* __restrict__ sc,
                                                   const float* __restrict__ bi,
                                                   ushort_t* __restrict__ xn,
                                                   const int* __restrict__ mask,
                                                   unsigned* __restrict__ bits) {
  __shared__ float red[8];
  __shared__ unsigned char nib[256];
  int bid = blockIdx.x, tid = threadIdx.x;
  if (bid < 4096) {
    const float* src = (bid < 1024) ? wq : (bid < 2048) ? wk : (bid < 3072) ? wv : wo;
    ushort_t* dst = (bid < 1024) ? wqb : (bid < 2048) ? wkb : (bid < 3072) ? wvb : wob;
    int i = (bid & 1023) * 256 + tid;
    fx4 v = *(const fx4*)&src[(size_t)i * 4];
    ushortx4 o;
#pragma unroll
    for (int j = 0; j < 4; ++j) o[j] = f2bf(v[j]);
    *(ushortx4*)&dst[(size_t)i * 4] = o;
  } else if (bid < 12288) {
    int row = bid - 4096;
    const float* xr = x + (size_t)row * 1024;
    fx4 v = *(const fx4*)&xr[tid * 4];
    float s = v[0] + v[1] + v[2] + v[3];
    float s2 = v[0] * v[0] + v[1] * v[1] + v[2] * v[2] + v[3] * v[3];
#pragma unroll
    for (int m = 32; m >= 1; m >>= 1) {
      s += __shfl_xor(s, m);
      s2 += __shfl_xor(s2, m);
    }
    int wave = tid >> 6;
    if ((tid & 63) == 0) { red[wave * 2] = s; red[wave * 2 + 1] = s2; }
    __syncthreads();
    s = red[0] + red[2] + red[4] + red[6];
    s2 = red[1] + red[3] + red[5] + red[7];
    float mu = s * (1.f / 1024.f);
    float var = s2 * (1.f / 1024.f) - mu * mu;
    float rs = rsqrtf(var + 1e-5f);
    fx4 scv = *(const fx4*)&sc[tid * 4];
    fx4 biv = *(const fx4*)&bi[tid * 4];
    ushortx4 o;
#pragma unroll
    for (int j = 0; j < 4; ++j) o[j] = f2bf((v[j] - mu) * rs * scv[j] + biv[j]);
    *(ushortx4*)&xn[(size_t)row * 1024 + tid * 4] = o;
  } else {
    int row = bid - 12288;
    ix4 m = *(const ix4*)&mask[(size_t)row * 1024 + tid * 4];
    nib[tid] = (unsigned char)((m[0] != 0 ? 1 : 0) | (m[1] != 0 ? 2 : 0) |
                               (m[2] != 0 ? 4 : 0) | (m[3] != 0 ? 8 : 0));
    __syncthreads();
    if (tid < 32) {
      unsigned w = 0;
#pragma unroll
      for (int j = 0; j < 8; ++j) w |= ((unsigned)nib[tid * 8 + j]) << (j * 4);
      bits[(size_t)row * 32 + tid] = w;
    }
  }
}

// ---- GEMM: C[M][N] = (A @ B^T + bias(n)) * scale(n); bias/scale select per 1024-col group ----
template <int F32OUT>
__global__ __launch_bounds__(256) void gemm_bt(const ushort_t* __restrict__ A,
                                               const ushort_t* __restrict__ B,
                                               const float* __restrict__ b0,
                                               const float* __restrict__ b1,
                                               const float* __restrict__ b2, void* C,
                                               int M, int N, int K, float os0, float os1) {
  __shared__ ushort_t lA[4096];  // [128][32] linear
  __shared__ ushort_t lB[4096];
  int bm = blockIdx.y * 128, bn = blockIdx.x * 128;
  int tid = threadIdx.x;
  int wave = tid >> 6, lane = tid & 63;
  int wm = (wave >> 1) * 64, wn = (wave & 1) * 64;
  int l15 = lane & 15, lg = lane >> 4;
  int r0 = tid >> 2, c0 = (tid & 3) * 8;
  int g1 = 256 + tid, r1 = g1 >> 2, c1 = (g1 & 3) * 8;
  int lb0 = (wave * 64) * 8;
  int lb1 = (256 + wave * 64) * 8;
  fx4 acc[4][4] = {};
  for (int k0 = 0; k0 < K; k0 += 32) {
    __syncthreads();
    gload16(&A[(size_t)(bm + r0) * K + k0 + c0], &lA[lb0]);
    gload16(&A[(size_t)(bm + r1) * K + k0 + c1], &lA[lb1]);
    gload16(&B[(size_t)(bn + r0) * K + k0 + c0], &lB[lb0]);
    gload16(&B[(size_t)(bn + r1) * K + k0 + c1], &lB[lb1]);
    __syncthreads();
    short8 af[4], bf[4];
#pragma unroll
    for (int i = 0; i < 4; ++i) af[i] = *(const short8*)&lA[(wm + i * 16 + l15) * 32 + lg * 8];
#pragma unroll
    for (int i = 0; i < 4; ++i) bf[i] = *(const short8*)&lB[(wn + i * 16 + l15) * 32 + lg * 8];
#pragma unroll
    for (int i = 0; i < 4; ++i)
#pragma unroll
      for (int j = 0; j < 4; ++j) acc[i][j] = MFMA(af[i], bf[j], acc[i][j]);
  }
#pragma unroll
  for (int j = 0; j < 4; ++j) {
    int n = bn + wn + j * 16 + l15;
    const float* bp = (n < 1024) ? b0 : (n < 2048) ? b1 : b2;
    float bv = bp[n & 1023];
    float sc = (n < 1024) ? os0 : os1;
#pragma unroll
    for (int i = 0; i < 4; ++i) {
      int mr = bm + wm + i * 16 + lg * 4;
#pragma unroll
      for (int r = 0; r < 4; ++r) {
        float val = (acc[i][j][r] + bv) * sc;
        if (F32OUT)
          ((float*)C)[(size_t)(mr + r) * N + n] = val;
        else
          ((ushort_t*)C)[(size_t)(mr + r) * N + n] = f2bf(val);
      }
    }
  }
}

// ---------------- B_all[bh][t][s] (fp8 e4m3) = sum_d q[...] * pos_k[t,s,d] ----------------
// r18 config restored (r19's g-loop variant regressed: VGPR 64 -> prefetch sunk).
// grid (2,1024), 512 threads, one 4-chunk group (64 s) per wave.
__device__ __forceinline__ void loadset(const float* base, int c, fx4* r) {
  const float* p = base + (size_t)c * 1024;
  r[0] = *(const fx4*)p;
  r[1] = *(const fx4*)(p + 4);
  r[2] = *(const fx4*)(p + 32);
  r[3] = *(const fx4*)(p + 36);
}
__device__ __forceinline__ void cvtset(const fx4* r, short8& f0, short8& f1) {
#pragma unroll
  for (int j = 0; j < 4; ++j) {
    f0[j] = (short)f2bf(r[0][j]); f0[j + 4] = (short)f2bf(r[1][j]);
    f1[j] = (short)f2bf(r[2][j]); f1[j + 4] = (short)f2bf(r[3][j]);
  }
}

__global__ __launch_bounds__(512, 4) void ball_kernel(const ushort_t* __restrict__ qkv,
                                                      const float* __restrict__ pos_k,
                                                      unsigned char* __restrict__ B8) {
  __shared__ ushort_t lq[128 * 64];  // rows of 128 B, col-byte ^= (row&7)<<4
  int t = blockIdx.y, sx = blockIdx.x;
  int tid = threadIdx.x, wave = tid >> 6, lane = tid & 63, l15 = lane & 15, lg = lane >> 4;
  const float* pk = pos_k + (size_t)t * 65536;
  int sw = sx * 512 + wave * 64;
  const float* base = pk + (size_t)(sw + l15) * 64 + lg * 8;

  fx4 raw[4][4];
#pragma unroll
  for (int c = 0; c < 4; ++c) loadset(base, c, raw[c]);

  // stage q[t]: 128 bh-rows x 64 bf16 (16 KB), swizzled (covers prologue latency)
#pragma unroll
  for (int it = 0; it < 2; ++it) {
    int u = tid + it * 512;           // 0..1023 16B-units
    int row = u >> 3, cu = u & 7;     // row=bh, cu=16B col unit
    ushort8 vv = *(const ushort8*)&qkv[((size_t)((row >> 4) * 1024 + t)) * 3072 + (row & 15) * 64 + cu * 8];
    *(ushort8*)&lq[(row * 128 + ((cu * 16) ^ ((row & 7) << 4))) >> 1] = vv;
  }
  __syncthreads();

  short8 af0[4], af1[4];
#pragma unroll
  for (int c = 0; c < 4; ++c) cvtset(raw[c], af0[c], af1[c]);

#pragma unroll
  for (int j = 0; j < 8; ++j) {
    int row_ = j * 16 + l15;
    int cb_ = (row_ & 7) << 4;
    short8 q0 = *(const short8*)&lq[(row_ * 128 + ((lg * 16) ^ cb_)) >> 1];
    short8 q1 = *(const short8*)&lq[(row_ * 128 + ((64 + lg * 16) ^ cb_)) >> 1];
    fx4 z = {};
    size_t rb = ((size_t)row_ << 20) + (size_t)t * 1024 + (size_t)sw;
#pragma unroll
    for (int c = 0; c < 4; ++c) {
      fx4 a = MFMA(af0[c], q0, z);
      a = MFMA(af1[c], q1, a);
      int u = __builtin_amdgcn_cvt_pk_fp8_f32(a[0], a[1], 0, false);
      u = __builtin_amdgcn_cvt_pk_fp8_f32(a[2], a[3], u, true);
      *(unsigned*)&B8[rb + c * 16 + lg * 4] = (unsigned)u;
    }
  }
}

// ---------------- flash attention v8 (r16 config): 256 thr, 2 t-tiles/wave ----------------
__global__ __launch_bounds__(256) void attn_kernel(const ushort_t* __restrict__ qkv,
                                                   const unsigned char* __restrict__ B8,
                                                   const unsigned* __restrict__ mbits,
                                                   ushort_t* __restrict__ out) {
  __shared__ ushort_t lK[64][72];
  __shared__ ushort_t lVt[64][72];
  __shared__ ushort_t lP[4][2][16][72];
  int bh = blockIdx.y, b = bh >> 4, h = bh & 15;
  int t0 = blockIdx.x * 128;
  int tid = threadIdx.x, wave = tid >> 6, lane = tid & 63, l15 = lane & 15, lg = lane >> 4;
  int twA = t0 + wave * 16, twB = twA + 64;
  short8 qfA[2], qfB[2];
#pragma unroll
  for (int ks = 0; ks < 2; ++ks) {
    qfA[ks] = *(const short8*)&qkv[((size_t)(b * 1024 + twA + l15)) * 3072 + h * 64 + ks * 32 + lg * 8];
    qfB[ks] = *(const short8*)&qkv[((size_t)(b * 1024 + twB + l15)) * 3072 + h * 64 + ks * 32 + lg * 8];
  }
  fx4 oA[4] = {}, oB[4] = {};
  float lsumA = 0.f, lsumB = 0.f;
  const unsigned* mrowA = &mbits[((size_t)b * 1024 + twA + l15) * 32];
  const unsigned* mrowB = &mbits[((size_t)b * 1024 + twB + l15) * 32];
  size_t ballA = ((size_t)bh * 1024 + twA + l15) * 1024;
  size_t ballB = ((size_t)bh * 1024 + twB + l15) * 1024;

  int rs = tid >> 3, c8g = tid & 7, c8 = c8g * 8;  // staging: rows rs, rs+32
  const ushort_t* kbase = &qkv[((size_t)(b * 1024) + rs) * 3072 + 1024 + h * 64 + c8];
  const ushort_t* vbase = &qkv[((size_t)(b * 1024) + rs) * 3072 + 2048 + h * 64 + c8];
  ushort8 kr0 = *(const ushort8*)(kbase);
  ushort8 kr1 = *(const ushort8*)(kbase + 32 * 3072);
  ushort8 vr0 = *(const ushort8*)(vbase);
  ushort8 vr1 = *(const ushort8*)(vbase + 32 * 3072);
  int vs0 = (rs + 8 * c8g) & 63;        // rotated s-slot for row rs
  int vs1 = (rs + 32 + 8 * c8g) & 63;   // rotated s-slot for row rs+32

  // prefetched B_all (fp8) + mask for s0 = 0
  unsigned n8A[4], n8B[4];
#pragma unroll
  for (int mf = 0; mf < 4; ++mf) {
    n8A[mf] = *(const unsigned*)&B8[ballA + mf * 16 + lg * 4];
    n8B[mf] = *(const unsigned*)&B8[ballB + mf * 16 + lg * 4];
  }
  uint2 nmA = *(const uint2*)&mrowA[0];
  uint2 nmB = *(const uint2*)&mrowB[0];

  for (int s0 = 0; s0 < 1024; s0 += 64) {
    __syncthreads();
    *(ushort8*)&lK[rs][c8] = kr0;
    *(ushort8*)&lK[rs + 32][c8] = kr1;
#pragma unroll
    for (int j = 0; j < 8; ++j) {
      lVt[c8 + j][vs0] = vr0[j];
      lVt[c8 + j][vs1] = vr1[j];
    }
    __syncthreads();
    if (s0 + 64 < 1024) {
      size_t off = (size_t)(s0 + 64) * 3072;
      kr0 = *(const ushort8*)(kbase + off);
      kr1 = *(const ushort8*)(kbase + off + 32 * 3072);
      vr0 = *(const ushort8*)(vbase + off);
      vr1 = *(const ushort8*)(vbase + off + 32 * 3072);
    }
    __builtin_amdgcn_sched_barrier(0);
    unsigned long long wbA = ((unsigned long long)nmA.y << 32) | nmA.x;
    unsigned long long wbB = ((unsigned long long)nmB.y << 32) | nmB.x;
    // S^T tiles: kf read once, feeds both tiles (prescaled by QSCALE)
    float pA[16], pB[16];
#pragma unroll
    for (int mf = 0; mf < 4; ++mf) {
      short8 kf0 = *(const short8*)&lK[mf * 16 + l15][lg * 8];
      short8 kf1 = *(const short8*)&lK[mf * 16 + l15][32 + lg * 8];
      fx4 cA = {}, cB = {};
      cA = MFMA(kf0, qfA[0], cA);
      cA = MFMA(kf1, qfA[1], cA);
      cB = MFMA(kf0, qfB[0], cB);
      cB = MFMA(kf1, qfB[1], cB);
      fx4 dA = fp8x4(n8A[mf]);
      fx4 dB = fp8x4(n8B[mf]);
#pragma unroll
      for (int r = 0; r < 4; ++r) {
        pA[mf * 4 + r] = exp2f(cA[r] + dA[r]);
        pB[mf * 4 + r] = exp2f(cB[r] + dB[r]);
      }
    }
    // mask slow path (all-ones rows skip)
    if (!__all((wbA == ~0ull) && (wbB == ~0ull))) {
#pragma unroll
      for (int i = 0; i < 16; ++i) {
        int sl = (i >> 2) * 16 + lg * 4 + (i & 3);
        if (!((wbA >> sl) & 1ull)) pA[i] = 0.f;
        if (!((wbB >> sl) & 1ull)) pB[i] = 0.f;
      }
    }
    // prefetch next iteration's B_all + mask (lands during PV + next staging)
    if (s0 + 64 < 1024) {
#pragma unroll
      for (int mf = 0; mf < 4; ++mf) {
        n8A[mf] = *(const unsigned*)&B8[ballA + s0 + 64 + mf * 16 + lg * 4];
        n8B[mf] = *(const unsigned*)&B8[ballB + s0 + 64 + mf * 16 + lg * 4];
      }
      nmA = *(const uint2*)&mrowA[(s0 + 64) >> 5];
      nmB = *(const uint2*)&mrowB[(s0 + 64) >> 5];
    }
    __builtin_amdgcn_sched_barrier(0);
    float psA = 0.f, psB = 0.f;
#pragma unroll
    for (int i = 0; i < 16; ++i) { psA += pA[i]; psB += pB[i]; }
    lsumA += psA;
    lsumB += psB;
    // pack P -> lP (both tiles)
#pragma unroll
    for (int mf = 0; mf < 4; ++mf) {
      ushortx4 pk4A, pk4B;
#pragma unroll
      for (int r = 0; r < 4; ++r) { pk4A[r] = f2bf(pA[mf * 4 + r]); pk4B[r] = f2bf(pB[mf * 4 + r]); }
      *(ushortx4*)&lP[wave][0][l15][mf * 16 + lg * 4] = pk4A;
      *(ushortx4*)&lP[wave][1][l15][mf * 16 + lg * 4] = pk4B;
    }
    // PV: vf read once, feeds both tiles
#pragma unroll
    for (int ks = 0; ks < 2; ++ks) {
      short8 pfA = *(const short8*)&lP[wave][0][l15][ks * 32 + lg * 8];
      short8 pfB = *(const short8*)&lP[wave][1][l15][ks * 32 + lg * 8];
#pragma unroll
      for (int nf = 0; nf < 4; ++nf) {
        int d_ = nf * 16 + l15;
        int sb_ = (ks * 32 + lg * 8 + 8 * (d_ >> 3)) & 63;
        short8 vf = *(const short8*)&lVt[d_][sb_];
        oA[nf] = MFMA(pfA, vf, oA[nf]);
        oB[nf] = MFMA(pfB, vf, oB[nf]);
      }
    }
  }
  // final denominators
  lsumA += __shfl_xor(lsumA, 16);
  lsumA += __shfl_xor(lsumA, 32);
  lsumB += __shfl_xor(lsumB, 16);
  lsumB += __shfl_xor(lsumB, 32);
  float rlA = (lsumA > 0.f) ? 1.f / lsumA : 0.f;
  float rlB = (lsumB > 0.f) ? 1.f / lsumB : 0.f;
  float rwA[4], rwB[4];
#pragma unroll
  for (int r = 0; r < 4; ++r) {
    rwA[r] = __shfl(rlA, lg * 4 + r);
    rwB[r] = __shfl(rlB, lg * 4 + r);
  }
#pragma unroll
  for (int nf = 0; nf < 4; ++nf)
#pragma unroll
    for (int r = 0; r < 4; ++r) {
      out[((size_t)(b * 1024 + twA + lg * 4 + r)) * 1024 + h * 64 + nf * 16 + l15] =
          f2bf(oA[nf][r] * rwA[r]);
      out[((size_t)(b * 1024 + twB + lg * 4 + r)) * 1024 + h * 64 + nf * 16 + l15] =
          f2bf(oB[nf][r] * rwB[r]);
    }
}

extern "C" void kernel_launch(void* const* d_in, const int* in_sizes, int n_in, void* d_out,
                              int out_size, void* d_ws, size_t ws_size, hipStream_t stream) {
  (void)in_sizes; (void)n_in; (void)out_size; (void)ws_size;
  const float* x = (const float*)d_in[0];
  const float* pos_k = (const float*)d_in[1];
  const int* mask = (const int*)d_in[2];
  const float* ln_scale = (const float*)d_in[3];
  const float* ln_bias = (const float*)d_in[4];
  const float* wq = (const float*)d_in[5];
  const float* bq = (const float*)d_in[6];
  const float* wk = (const float*)d_in[7];
  const float* bk = (const float*)d_in[8];
  const float* wv = (const float*)d_in[9];
  const float* bv = (const float*)d_in[10];
  const float* wo = (const float*)d_in[11];
  const float* bo = (const float*)d_in[12];
  float* out = (float*)d_out;
  char* ws = (char*)d_ws;
  const size_t MB = 1ull << 20;
  ushort_t* xn = (ushort_t*)(ws + 0 * MB);    // 16 MB
  ushort_t* qkv = (ushort_t*)(ws + 16 * MB);  // 48 MB fused [8192][3072] (q|k|v)
  ushort_t* ao = (ushort_t*)(ws + 64 * MB);   // 16 MB
  ushort_t* wqb = (ushort_t*)(ws + 80 * MB);  // wq|wk|wv contiguous = [3072][1024]
  ushort_t* wkb = (ushort_t*)(ws + 82 * MB);
  ushort_t* wvb = (ushort_t*)(ws + 84 * MB);
  ushort_t* wob = (ushort_t*)(ws + 86 * MB);
  unsigned char* ball8 = (unsigned char*)(ws + 88 * MB);  // 128 MB fp8
  unsigned* mbits = (unsigned*)(ws + 216 * MB);  // 1 MB own region (ws >= 344 MB, r0)

  prep_kernel<<<20480, 256, 0, stream>>>(wq, wk, wv, wo, wqb, wkb, wvb, wob, x, ln_scale,
                                         ln_bias, xn, mask, mbits);
  // fused QKV GEMM: N = 3072, q-columns prescaled by QSCALE
  gemm_bt<0><<<dim3(24, 64), 256, 0, stream>>>(xn, wqb, bq, bk, bv, qkv, 8192, 3072, 1024,
                                               QSCALE, 1.f);
  ball_kernel<<<dim3(2, 1024), 512, 0, stream>>>(qkv, pos_k, ball8);
  attn_kernel<<<dim3(8, 128), 256, 0, stream>>>(qkv, ball8, mbits, ao);
  gemm_bt<1><<<dim3(8, 64), 256, 0, stream>>>(ao, wob, bo, bo, bo, out, 8192, 1024, 1024,
                                              1.f, 1.f);
}